// Round 2
// baseline (77.331 us; speedup 1.0000x reference)
//
#include <hip/hip_runtime.h>

// ToroidalSOM distances: out[b][n] = ||w_n||^2 + ||x_b||^2 - 2*dot(w_n, x_b)
// B=128, D=64, N=16384 neurons. fp32.
//
// Two kernels:
//  A (prep): transpose w (n-major) -> wt (chunk-major float4: wt[i][n]) in d_ws
//            so the main kernel's weight loads are lane-coalesced. Also computes
//            x2[b] = ||x_b||^2 via one wave-reduction in each of blocks 0..127.
//  B (main): thread = 1 neuron, 16 batches. w row: 16 coalesced dwordx4 from wt.
//            x is wave-uniform -> scalar loads (constant cache), NO LDS, no
//            barriers. 4 independent FMA accumulators for latency cover.

#define SOM_B   128
#define SOM_D   64
#define SOM_N   16384
#define SOM_BT  16
#define SOM_TPB 256

__global__ __launch_bounds__(SOM_TPB)
void som_prep(const float* __restrict__ x,
              const float* __restrict__ w,
              float4* __restrict__ wt,
              float* __restrict__ x2) {
    const int tid = threadIdx.x;
    const int j   = blockIdx.x * SOM_TPB + tid;   // 0 .. 262143 (float4 id)
    const int i   = j >> 14;                      // chunk 0..15
    const int n   = j & (SOM_N - 1);              // neuron
    const float4* w4 = (const float4*)w;
    // write coalesced (j consecutive); read is the one-time scattered side
    wt[j] = w4[(n << 4) | i];

    // ||x_b||^2: blocks 0..127 each reduce one batch with their first wave
    if (blockIdx.x < SOM_B && tid < 64) {
        float v = x[(blockIdx.x << 6) + tid];
        float s = v * v;
        #pragma unroll
        for (int off = 32; off > 0; off >>= 1)
            s += __shfl_down(s, off, 64);
        if (tid == 0) x2[blockIdx.x] = s;
    }
}

__global__ __launch_bounds__(SOM_TPB, 2)
void som_main(const float* __restrict__ x,
              const float4* __restrict__ wt,
              const float* __restrict__ x2,
              float* __restrict__ out) {
    const int tid = threadIdx.x;
    const int n   = blockIdx.x * SOM_TPB + tid;   // neuron
    const int b0  = blockIdx.y * SOM_BT;          // first batch

    // coalesced weight row load: lane-consecutive n for each chunk i
    float4 wr[16];
    #pragma unroll
    for (int i = 0; i < 16; ++i) wr[i] = wt[(i << 14) + n];

    float wn2 = 0.f;
    #pragma unroll
    for (int i = 0; i < 16; ++i)
        wn2 += wr[i].x * wr[i].x + wr[i].y * wr[i].y
             + wr[i].z * wr[i].z + wr[i].w * wr[i].w;

    const float4* x4 = (const float4*)x;
    float* op = out + (size_t)b0 * SOM_N + n;

    #pragma unroll
    for (int b = 0; b < SOM_BT; ++b) {
        const float4* xb = x4 + ((b0 + b) << 4);  // wave-uniform -> s_load
        float a0 = 0.f, a1 = 0.f, a2 = 0.f, a3 = 0.f;
        #pragma unroll
        for (int i = 0; i < 16; i += 4) {
            float4 xv0 = xb[i + 0];
            float4 xv1 = xb[i + 1];
            float4 xv2 = xb[i + 2];
            float4 xv3 = xb[i + 3];
            a0 += wr[i + 0].x * xv0.x + wr[i + 0].y * xv0.y
                + wr[i + 0].z * xv0.z + wr[i + 0].w * xv0.w;
            a1 += wr[i + 1].x * xv1.x + wr[i + 1].y * xv1.y
                + wr[i + 1].z * xv1.z + wr[i + 1].w * xv1.w;
            a2 += wr[i + 2].x * xv2.x + wr[i + 2].y * xv2.y
                + wr[i + 2].z * xv2.z + wr[i + 2].w * xv2.w;
            a3 += wr[i + 3].x * xv3.x + wr[i + 3].y * xv3.y
                + wr[i + 3].z * xv3.z + wr[i + 3].w * xv3.w;
        }
        float acc = (a0 + a1) + (a2 + a3);
        op[(size_t)b * SOM_N] = fmaf(-2.f, acc, wn2 + x2[b0 + b]);
    }
}

extern "C" void kernel_launch(void* const* d_in, const int* in_sizes, int n_in,
                              void* d_out, int out_size, void* d_ws, size_t ws_size,
                              hipStream_t stream) {
    const float* x = (const float*)d_in[0];   // (128, 64)
    const float* w = (const float*)d_in[1];   // (128, 128, 64)
    float* out = (float*)d_out;               // (128, 128, 128)

    float4* wt = (float4*)d_ws;                              // 4 MB
    float*  x2 = (float*)((char*)d_ws + SOM_N * SOM_D * 4);  // 512 B

    // A: 262144 float4s / 256 threads = 1024 blocks
    som_prep<<<dim3((SOM_N * SOM_D / 4) / SOM_TPB), dim3(SOM_TPB), 0, stream>>>(x, w, wt, x2);
    // B: (64, 8)
    som_main<<<dim3(SOM_N / SOM_TPB, SOM_B / SOM_BT), dim3(SOM_TPB), 0, stream>>>(x, wt, x2, out);
}

// Round 3
// 71.763 us; speedup vs baseline: 1.0776x; 1.0776x over previous
//
#include <hip/hip_runtime.h>

// ToroidalSOM distances: out[b][n] = ||w_n||^2 + ||x_b||^2 - 2*dot(w_n, x_b)
// B=128, D=64, N=16384 neurons, fp32. Output (B, R, C) = (128, 128, 128).
//
// Single kernel (two-kernel prep variant regressed 8.6 us on launch+prep).
// Per-pipe budget (per CU, 8 waves):
//   VALU: 1024 FMA/thread -> 4096 cyc/SIMD ~= 1.7 us  <- target bound
//   LDS : only x2 broadcast reads (16/thread)          ~ negligible
//   VMEM: one-time w-gather (16 instr/thread) + x s_loads (scalarized)
// R1's mistake: inner-loop x via ds_read_b128 (256/thread) = ~10 us LDS pipe.
// Here x is fetched through a wave-uniform pointer so the compiler emits
// s_load -> SGPRs; inner loop is v_fmac v, s, v with no per-FMA memory op.

#define SOM_B   128
#define SOM_D   64
#define SOM_N   16384
#define SOM_BT  16
#define SOM_TPB 256

__global__ __launch_bounds__(SOM_TPB, 2)
void som_dist_kernel(const float* __restrict__ x,
                     const float* __restrict__ w,
                     float* __restrict__ out) {
    __shared__ float x2s[SOM_BT];

    const int tid = threadIdx.x;
    const int n   = blockIdx.x * SOM_TPB + tid;   // neuron (coalesced store dim)
    const int b0  = blockIdx.y * SOM_BT;          // first batch of tile

    const float4* x4 = (const float4*)x;

    // 1) Issue this neuron's weight-row loads (one-time gather; overlaps the
    //    x2 straggler below and the barrier).
    float4 wr[16];
    {
        const float4* wg = (const float4*)(w + (size_t)n * SOM_D);
        #pragma unroll
        for (int i = 0; i < 16; ++i) wr[i] = wg[i];
    }

    // 2) ||x_b||^2 for the block's 16 batches (threads 0..15, one-time).
    if (tid < SOM_BT) {
        const float4* xr = x4 + ((b0 + tid) << 4);
        float s0 = 0.f, s1 = 0.f, s2 = 0.f, s3 = 0.f;
        #pragma unroll
        for (int i = 0; i < 16; i += 4) {
            float4 v0 = xr[i + 0], v1 = xr[i + 1], v2 = xr[i + 2], v3 = xr[i + 3];
            s0 += v0.x * v0.x + v0.y * v0.y + v0.z * v0.z + v0.w * v0.w;
            s1 += v1.x * v1.x + v1.y * v1.y + v1.z * v1.z + v1.w * v1.w;
            s2 += v2.x * v2.x + v2.y * v2.y + v2.z * v2.z + v2.w * v2.w;
            s3 += v3.x * v3.x + v3.y * v3.y + v3.z * v3.z + v3.w * v3.w;
        }
        x2s[tid] = (s0 + s1) + (s2 + s3);
    }

    float wn2 = 0.f;
    #pragma unroll
    for (int i = 0; i < 16; ++i)
        wn2 += wr[i].x * wr[i].x + wr[i].y * wr[i].y
             + wr[i].z * wr[i].z + wr[i].w * wr[i].w;

    __syncthreads();

    float* op = out + (size_t)b0 * SOM_N + n;

    // 3) Main loop: x loads are wave-uniform (blockIdx-derived address) ->
    //    scalarized to s_load; FMAs take the SGPR operand directly.
    #pragma unroll
    for (int b = 0; b < SOM_BT; ++b) {
        const float4* xb = x4 + ((b0 + b) << 4);
        float a0 = 0.f, a1 = 0.f, a2 = 0.f, a3 = 0.f;
        #pragma unroll
        for (int i = 0; i < 16; i += 4) {
            float4 xv0 = xb[i + 0];
            float4 xv1 = xb[i + 1];
            float4 xv2 = xb[i + 2];
            float4 xv3 = xb[i + 3];
            a0 += wr[i + 0].x * xv0.x + wr[i + 0].y * xv0.y
                + wr[i + 0].z * xv0.z + wr[i + 0].w * xv0.w;
            a1 += wr[i + 1].x * xv1.x + wr[i + 1].y * xv1.y
                + wr[i + 1].z * xv1.z + wr[i + 1].w * xv1.w;
            a2 += wr[i + 2].x * xv2.x + wr[i + 2].y * xv2.y
                + wr[i + 2].z * xv2.z + wr[i + 2].w * xv2.w;
            a3 += wr[i + 3].x * xv3.x + wr[i + 3].y * xv3.y
                + wr[i + 3].z * xv3.z + wr[i + 3].w * xv3.w;
        }
        float acc = (a0 + a1) + (a2 + a3);
        op[(size_t)b * SOM_N] = fmaf(-2.f, acc, wn2 + x2s[b]);
    }
}

extern "C" void kernel_launch(void* const* d_in, const int* in_sizes, int n_in,
                              void* d_out, int out_size, void* d_ws, size_t ws_size,
                              hipStream_t stream) {
    const float* x = (const float*)d_in[0];   // (128, 64)
    const float* w = (const float*)d_in[1];   // (128, 128, 64)
    float* out = (float*)d_out;               // (128, 128, 128)

    dim3 grid(SOM_N / SOM_TPB, SOM_B / SOM_BT);   // (64, 8) = 512 blocks
    dim3 block(SOM_TPB);
    som_dist_kernel<<<grid, block, 0, stream>>>(x, w, out);
}

// Round 5
// 69.078 us; speedup vs baseline: 1.1195x; 1.0389x over previous
//
#include <hip/hip_runtime.h>

// ToroidalSOM distances: out[b][n] = ||w_n||^2 + ||x_b||^2 - 2*dot(w_n, x_b)
// B=128, D=64, N=16384 neurons, fp32. Output (128, 128, 128).
//
// R5: R4's coalesced w-staging, but LDS < 64 KB. R4 used 65,600 B static LDS
// (just over the 64 KB boundary) and corrupted under graph replay after a
// correct first launch — retreat below the limit rather than debug it.
//
// Two-phase staging through one 32 KB buffer:
//   stage rows 0..127 (coalesced) -> sync -> waves 0-1 copy their row to
//   registers -> sync -> stage rows 128..255 -> sync -> waves 2-3 copy.
// Chunk-rotate swizzle slot = row*16 + ((chunk+row)&15) on both sides
// (write/read mappings identical -> correct; spreads b128 bank traffic).
//
// Main loop (as R3): w in 64 VGPRs, x via wave-uniform pointer (scalar path),
// 4 independent accumulators, coalesced stores.

#define SOM_B   128
#define SOM_D   64
#define SOM_N   16384
#define SOM_BT  16
#define SOM_TPB 256
#define HROWS   128   // rows per staging phase

__global__ __launch_bounds__(SOM_TPB)
void som_dist_kernel(const float* __restrict__ x,
                     const float* __restrict__ w,
                     float* __restrict__ out) {
    __shared__ float4 wtile[HROWS * 16];   // 32 KB
    __shared__ float  x2s[SOM_BT];         // 64 B

    const int tid = threadIdx.x;
    const int n   = blockIdx.x * SOM_TPB + tid;   // neuron (coalesced store dim)
    const int b0  = blockIdx.y * SOM_BT;          // first batch of tile

    const float4* x4 = (const float4*)x;
    const float4* wg = (const float4*)w + ((size_t)blockIdx.x << 12); // block's 256 rows

    // ||x_b||^2 for the block's 16 batches (threads 0..15; overlaps staging).
    if (tid < SOM_BT) {
        const float4* xr = x4 + ((b0 + tid) << 4);
        float s0 = 0.f, s1 = 0.f, s2 = 0.f, s3 = 0.f;
        #pragma unroll
        for (int i = 0; i < 16; i += 4) {
            float4 v0 = xr[i + 0], v1 = xr[i + 1], v2 = xr[i + 2], v3 = xr[i + 3];
            s0 += v0.x * v0.x + v0.y * v0.y + v0.z * v0.z + v0.w * v0.w;
            s1 += v1.x * v1.x + v1.y * v1.y + v1.z * v1.z + v1.w * v1.w;
            s2 += v2.x * v2.x + v2.y * v2.y + v2.z * v2.z + v2.w * v2.w;
            s3 += v3.x * v3.x + v3.y * v3.y + v3.z * v3.z + v3.w * v3.w;
        }
        x2s[tid] = (s0 + s1) + (s2 + s3);
    }

    float4 wr[16];
    const int r = tid & (HROWS - 1);   // row within a phase

    // Phase 0: stage rows 0..127 (float4 j in [0, 2048)), coalesced.
    #pragma unroll
    for (int k = 0; k < 8; ++k) {
        int j     = k * SOM_TPB + tid;
        float4 v  = wg[j];
        int row   = j >> 4;            // 0..127
        int chunk = j & 15;
        wtile[(row << 4) + ((chunk + row) & 15)] = v;
    }
    __syncthreads();

    if (tid < HROWS) {                 // waves 0-1: copy row r=tid to registers
        #pragma unroll
        for (int i = 0; i < 16; ++i)
            wr[i] = wtile[(r << 4) + ((i + r) & 15)];
    }
    __syncthreads();

    // Phase 1: stage rows 128..255 (float4 j in [2048, 4096)) into same buffer.
    #pragma unroll
    for (int k = 8; k < 16; ++k) {
        int j     = k * SOM_TPB + tid;
        float4 v  = wg[j];
        int row   = (j >> 4) - HROWS;  // 0..127
        int chunk = j & 15;
        wtile[(row << 4) + ((chunk + row) & 15)] = v;
    }
    __syncthreads();

    if (tid >= HROWS) {                // waves 2-3: copy row r=tid-128
        #pragma unroll
        for (int i = 0; i < 16; ++i)
            wr[i] = wtile[(r << 4) + ((i + r) & 15)];
    }

    float wn2 = 0.f;
    #pragma unroll
    for (int i = 0; i < 16; ++i)
        wn2 += wr[i].x * wr[i].x + wr[i].y * wr[i].y
             + wr[i].z * wr[i].z + wr[i].w * wr[i].w;

    float* op = out + (size_t)b0 * SOM_N + n;

    // Main loop: x addresses are wave-uniform -> scalar loads.
    #pragma unroll
    for (int b = 0; b < SOM_BT; ++b) {
        const float4* xb = x4 + ((b0 + b) << 4);
        float a0 = 0.f, a1 = 0.f, a2 = 0.f, a3 = 0.f;
        #pragma unroll
        for (int i = 0; i < 16; i += 4) {
            float4 xv0 = xb[i + 0];
            float4 xv1 = xb[i + 1];
            float4 xv2 = xb[i + 2];
            float4 xv3 = xb[i + 3];
            a0 += wr[i + 0].x * xv0.x + wr[i + 0].y * xv0.y
                + wr[i + 0].z * xv0.z + wr[i + 0].w * xv0.w;
            a1 += wr[i + 1].x * xv1.x + wr[i + 1].y * xv1.y
                + wr[i + 1].z * xv1.z + wr[i + 1].w * xv1.w;
            a2 += wr[i + 2].x * xv2.x + wr[i + 2].y * xv2.y
                + wr[i + 2].z * xv2.z + wr[i + 2].w * xv2.w;
            a3 += wr[i + 3].x * xv3.x + wr[i + 3].y * xv3.y
                + wr[i + 3].z * xv3.z + wr[i + 3].w * xv3.w;
        }
        float acc = (a0 + a1) + (a2 + a3);
        op[(size_t)b * SOM_N] = fmaf(-2.f, acc, wn2 + x2s[b]);
    }
}

extern "C" void kernel_launch(void* const* d_in, const int* in_sizes, int n_in,
                              void* d_out, int out_size, void* d_ws, size_t ws_size,
                              hipStream_t stream) {
    const float* x = (const float*)d_in[0];   // (128, 64)
    const float* w = (const float*)d_in[1];   // (128, 128, 64)
    float* out = (float*)d_out;               // (128, 128, 128)

    dim3 grid(SOM_N / SOM_TPB, SOM_B / SOM_BT);   // (64, 8) = 512 blocks
    dim3 block(SOM_TPB);
    som_dist_kernel<<<grid, block, 0, stream>>>(x, w, out);
}